// Round 4
// baseline (331.105 us; speedup 1.0000x reference)
//
#include <hip/hip_runtime.h>
#include <hip/hip_bf16.h>
#include <math.h>

#define TT   1024
#define HH   1024
#define II   512
#define EE   32
#define NE   40
#define TOPK 4
#define CAP  1024

typedef __attribute__((ext_vector_type(4))) short short4v;
typedef __attribute__((ext_vector_type(8))) short short8v;
typedef __attribute__((ext_vector_type(4))) float floatx4;

// fp32 -> bf16, RNE (manual fallback)
static __device__ __forceinline__ short f2bf(float f) {
    unsigned u = __float_as_uint(f);
    unsigned r = (u + 0x7fffu + ((u >> 16) & 1u)) >> 16;
    return (short)(r & 0xffffu);
}
static __device__ __forceinline__ float bf2f(short s) {
    return __uint_as_float(((unsigned)(unsigned short)s) << 16);
}

#if defined(__has_builtin)
#if __has_builtin(__builtin_amdgcn_cvt_pk_bf16_f32)
#define HAVE_PK_BF16 1
#endif
#endif

// pack 2 fp32 -> 2 bf16 in one u32 (lo=a, hi=b)
static __device__ __forceinline__ unsigned pk2(float a, float b) {
#ifdef HAVE_PK_BF16
    typedef __attribute__((ext_vector_type(2))) __bf16 bf2t;
    union { bf2t v; unsigned u; } cv;
    cv.v = __builtin_amdgcn_cvt_pk_bf16_f32(a, b);
    return cv.u;
#else
    return (unsigned)(unsigned short)f2bf(a) | ((unsigned)(unsigned short)f2bf(b) << 16);
#endif
}
static __device__ __forceinline__ short4v cvt4(float4 v) {
    union { unsigned u[2]; short4v s; } cv;
    cv.u[0] = pk2(v.x, v.y); cv.u[1] = pk2(v.z, v.w);
    return cv.s;
}

// ---------------- workspace layout (bytes) ----------------
// counts: int[EE]            @ 0
// topk_w: float[TT*TOPK]     @ 1024
// zero_w: float[TT]          @ 17408
// kexp:   int[TT*TOPK]       @ 21504
// slots:  int[EE*CAP]        @ 40960
// xb:     bf16[TT*HH]        @ 262144   (2 MB)
// hmid:   bf16[TT*TOPK*II]   @ 2359296  (4 MB)
// ydown:  bf16[TT*TOPK*HH]   @ 6553600  (8 MB)
#define WS_NEED_COMBINE 14942208ull

// ============== Kernel 0: x -> bf16 pre-convert ==============
__global__ __launch_bounds__(256) void xconv_kernel(
    const float* __restrict__ x, short* __restrict__ xb)
{
    size_t i = ((size_t)blockIdx.x * 256 + threadIdx.x) * 8;
    float4 a = *(const float4*)&x[i];
    float4 b = *(const float4*)&x[i + 4];
    union { unsigned u[4]; short8v s; } cv;
    cv.u[0] = pk2(a.x, a.y); cv.u[1] = pk2(a.z, a.w);
    cv.u[2] = pk2(b.x, b.y); cv.u[3] = pk2(b.z, b.w);
    *(short8v*)&xb[i] = cv.s;
}

// ============== Kernel 1: router — 1 wave / 2 tokens ==============
__global__ __launch_bounds__(64) void router_kernel(
    const float* __restrict__ x, const float* __restrict__ rw,
    const float* __restrict__ bias,
    float* __restrict__ topk_w, float* __restrict__ zero_w,
    int* __restrict__ kexp, int* __restrict__ counts, int* __restrict__ slots)
{
    const int t0 = blockIdx.x * 2;
    const int lane = threadIdx.x;

    // x for both tokens in registers
    float xv0[16], xv1[16];
    #pragma unroll
    for (int i = 0; i < 16; ++i) {
        xv0[i] = x[(size_t)t0 * HH + 64 * i + lane];
        xv1[i] = x[(size_t)(t0 + 1) * HH + 64 * i + lane];
    }

    float lg[2] = { -INFINITY, -INFINITY };
    for (int e0 = 0; e0 < NE; e0 += 4) {
        const float* r0 = rw + (size_t)e0 * HH;
        float p0[4] = {}, p1[4] = {};
        #pragma unroll
        for (int i = 0; i < 16; ++i) {
            int h = 64 * i + lane;
            float r[4];
            #pragma unroll
            for (int j = 0; j < 4; ++j) r[j] = r0[(size_t)j * HH + h];
            #pragma unroll
            for (int j = 0; j < 4; ++j) {
                p0[j] += xv0[i] * r[j];
                p1[j] += xv1[i] * r[j];
            }
        }
        #pragma unroll
        for (int j = 0; j < 4; ++j) {
            #pragma unroll
            for (int off = 32; off > 0; off >>= 1) {
                p0[j] += __shfl_xor(p0[j], off);
                p1[j] += __shfl_xor(p1[j], off);
            }
            if (lane == e0 + j) { lg[0] = p0[j]; lg[1] = p1[j]; }
        }
    }

    for (int j = 0; j < 2; ++j) {
        const int t = t0 + j;
        float ml = lg[j];
        float m = ml;
        #pragma unroll
        for (int off = 32; off > 0; off >>= 1) m = fmaxf(m, __shfl_xor(m, off));
        float pexp = (lane < NE) ? expf(ml - m) : 0.f;
        float s = pexp;
        #pragma unroll
        for (int off = 32; off > 0; off >>= 1) s += __shfl_xor(s, off);
        const float score = pexp / s;

        float val = (lane < NE) ? score + bias[lane] : -INFINITY;
        int   kidx[TOPK];
        float kw[TOPK];
        #pragma unroll
        for (int k = 0; k < TOPK; ++k) {
            float v = val; int idx = lane;
            #pragma unroll
            for (int off = 32; off > 0; off >>= 1) {
                float ov = __shfl_xor(v, off);
                int   oi = __shfl_xor(idx, off);
                if (ov > v || (ov == v && oi < idx)) { v = ov; idx = oi; }
            }
            kidx[k] = idx;
            kw[k]   = __shfl(score, idx);
            if (lane == idx) val = -INFINITY;
        }

        if (lane == 0) {
            float zw = 0.f;
            #pragma unroll
            for (int k = 0; k < TOPK; ++k) {
                int slot = t * TOPK + k;
                topk_w[slot] = kw[k];
                kexp[slot]   = kidx[k];
                if (kidx[k] < EE) {
                    int pos = atomicAdd(&counts[kidx[k]], 1);
                    slots[kidx[k] * CAP + pos] = slot;
                } else {
                    zw += kw[k];
                }
            }
            zero_w[t] = zw;
        }
    }
}

// ============== Kernel 2: gate_up bf16 MFMA + SiLU (weights pre-scaled) ==============
#define GM  128
#define GNP 32
#define GK  32
#define KP  40   // LDS pitch (bf16): 80 B, 16B-aligned

__global__ __launch_bounds__(256) void gate_up_kernel(
    const short* __restrict__ xb, const float* __restrict__ wgu,
    const int* __restrict__ counts, const int* __restrict__ slots,
    const float* __restrict__ topk_w, short* __restrict__ hmid)
{
    const int e = blockIdx.y;
    const int cnt = counts[e];
    const int m_base = blockIdx.z * GM;
    if (m_base >= cnt) return;
    const int c_base = blockIdx.x * GNP;

    __shared__ short As[2][GM * KP];
    __shared__ short Bs[2][2 * GNP * KP];
    __shared__ int   sl[GM];
    __shared__ float wvs[GM];

    const int tid = threadIdx.x;
    if (tid < GM) {
        int m = m_base + tid;
        int s = (m < cnt) ? slots[e * CAP + m] : -1;
        sl[tid]  = s;
        wvs[tid] = (s >= 0) ? topk_w[s] : 0.f;
    }
    __syncthreads();

    const float* wb = wgu + (size_t)e * (2 * II) * HH;

    // A staging (bf16, no cvt): 512 16B-chunks, 2/thread
    const int kcA = tid & 3;           // 8-elem group within row
    int rowA[2]; int slA[2]; const short* pA[2];
    #pragma unroll
    for (int it = 0; it < 2; ++it) {
        rowA[it] = (tid >> 2) + 64 * it;
        int s = sl[rowA[it]];
        slA[it] = s;
        pA[it] = xb + (size_t)((s >= 0 ? s : 0) >> 2) * HH + kcA * 8;
    }
    // B staging (fp32->bf16): 512 float4s, 2/thread
    const int kq = tid & 7;
    int rowB[2]; const float* pB[2];
    #pragma unroll
    for (int it = 0; it < 2; ++it) {
        rowB[it] = (tid >> 3) + 32 * it;
        int grow = (rowB[it] < GNP) ? (c_base + rowB[it]) : (II + c_base + rowB[it] - GNP);
        pB[it] = wb + (size_t)grow * HH + kq * 4;
    }

    const int lane = tid & 63;
    const int wv_  = tid >> 6;
    const int wy   = wv_ & 1;
    const int wx   = wv_ >> 1;
    const int quad = lane >> 4;
    const int mcol = lane & 15;

    floatx4 accg[4] = {};
    floatx4 accu[4] = {};

    short8v pa[2]; float4 pb[2];
    const short8v sz = { 0,0,0,0,0,0,0,0 };

    #pragma unroll
    for (int it = 0; it < 2; ++it) pa[it] = (slA[it] >= 0) ? *(const short8v*)(pA[it]) : sz;
    #pragma unroll
    for (int it = 0; it < 2; ++it) pb[it] = *(const float4*)(pB[it]);
    #pragma unroll
    for (int it = 0; it < 2; ++it) *(short8v*)&As[0][rowA[it] * KP + kcA * 8] = pa[it];
    #pragma unroll
    for (int it = 0; it < 2; ++it) *(short4v*)&Bs[0][rowB[it] * KP + kq * 4] = cvt4(pb[it]);
    __syncthreads();

    int p = 0;
    for (int k0 = 0; k0 < HH; k0 += GK) {
        const int kn = k0 + GK;
        const bool more = kn < HH;
        if (more) {
            #pragma unroll
            for (int it = 0; it < 2; ++it) pa[it] = (slA[it] >= 0) ? *(const short8v*)(pA[it] + kn) : sz;
            #pragma unroll
            for (int it = 0; it < 2; ++it) pb[it] = *(const float4*)(pB[it] + kn);
        }

        short8v a[4], bg, bu;
        #pragma unroll
        for (int i = 0; i < 4; ++i)
            a[i] = *(const short8v*)&As[p][(wy * 64 + i * 16 + mcol) * KP + quad * 8];
        bg = *(const short8v*)&Bs[p][(wx * 16 + mcol) * KP + quad * 8];
        bu = *(const short8v*)&Bs[p][(GNP + wx * 16 + mcol) * KP + quad * 8];
        #pragma unroll
        for (int i = 0; i < 4; ++i) {
            accg[i] = __builtin_amdgcn_mfma_f32_16x16x32_bf16(a[i], bg, accg[i], 0, 0, 0);
            accu[i] = __builtin_amdgcn_mfma_f32_16x16x32_bf16(a[i], bu, accu[i], 0, 0, 0);
        }

        if (more) {
            #pragma unroll
            for (int it = 0; it < 2; ++it) *(short8v*)&As[1 - p][rowA[it] * KP + kcA * 8] = pa[it];
            #pragma unroll
            for (int it = 0; it < 2; ++it) *(short4v*)&Bs[1 - p][rowB[it] * KP + kq * 4] = cvt4(pb[it]);
        }
        __syncthreads();
        p ^= 1;
    }

    // epilogue: hmid[slot][c] = w * silu(gate) * up   (pre-scale by routing weight)
    #pragma unroll
    for (int i = 0; i < 4; ++i) {
        #pragma unroll
        for (int r = 0; r < 4; ++r) {
            int m = wy * 64 + i * 16 + quad * 4 + r;
            int s = sl[m];
            if (s < 0) continue;
            float g = accg[i][r], u = accu[i][r];
            float valf = wvs[m] * g * u / (1.f + __expf(-g));
            hmid[(size_t)s * II + c_base + wx * 16 + mcol] = f2bf(valf);
        }
    }
}

// ============== Kernel 3: down bf16 MFMA ==============
#define DM 128
#define DN 64

template<int WRITE_Y>
__global__ __launch_bounds__(256) void down_kernel_t(
    const short* __restrict__ hmid, const float* __restrict__ wd,
    const int* __restrict__ counts, const int* __restrict__ slots,
    short* __restrict__ ydown, float* __restrict__ out)
{
    const int e = blockIdx.y;
    const int cnt = counts[e];
    const int m_base = blockIdx.z * DM;
    if (m_base >= cnt) return;
    const int n_base = blockIdx.x * DN;

    __shared__ short As[2][DM * KP];
    __shared__ short Bs[2][DN * KP];
    __shared__ int   sl[DM];

    const int tid = threadIdx.x;
    if (tid < DM) {
        int m = m_base + tid;
        sl[tid] = (m < cnt) ? slots[e * CAP + m] : -1;
    }
    __syncthreads();

    const float* wb = wd + (size_t)e * HH * II;

    const int kcA = tid & 3;
    int rowA[2]; int slA[2]; const short* pA[2];
    #pragma unroll
    for (int it = 0; it < 2; ++it) {
        rowA[it] = (tid >> 2) + 64 * it;
        int s = sl[rowA[it]];
        slA[it] = s;
        pA[it] = hmid + (size_t)(s >= 0 ? s : 0) * II + kcA * 8;
    }
    const int kq = tid & 7;
    int rowB[2]; const float* pB[2];
    #pragma unroll
    for (int it = 0; it < 2; ++it) {
        rowB[it] = (tid >> 3) + 32 * it;
        pB[it] = wb + (size_t)(n_base + rowB[it]) * II + kq * 4;
    }

    const int lane = tid & 63;
    const int wv_  = tid >> 6;
    const int wy   = wv_ & 1;
    const int wx   = wv_ >> 1;
    const int quad = lane >> 4;
    const int mcol = lane & 15;

    floatx4 acc[4][2] = {};

    short8v pa[2]; float4 pb[2];
    const short8v sz = { 0,0,0,0,0,0,0,0 };

    #pragma unroll
    for (int it = 0; it < 2; ++it) pa[it] = (slA[it] >= 0) ? *(const short8v*)(pA[it]) : sz;
    #pragma unroll
    for (int it = 0; it < 2; ++it) pb[it] = *(const float4*)(pB[it]);
    #pragma unroll
    for (int it = 0; it < 2; ++it) *(short8v*)&As[0][rowA[it] * KP + kcA * 8] = pa[it];
    #pragma unroll
    for (int it = 0; it < 2; ++it) *(short4v*)&Bs[0][rowB[it] * KP + kq * 4] = cvt4(pb[it]);
    __syncthreads();

    int p = 0;
    for (int k0 = 0; k0 < II; k0 += GK) {
        const int kn = k0 + GK;
        const bool more = kn < II;
        if (more) {
            #pragma unroll
            for (int it = 0; it < 2; ++it) pa[it] = (slA[it] >= 0) ? *(const short8v*)(pA[it] + kn) : sz;
            #pragma unroll
            for (int it = 0; it < 2; ++it) pb[it] = *(const float4*)(pB[it] + kn);
        }

        short8v a[4], b[2];
        #pragma unroll
        for (int i = 0; i < 4; ++i)
            a[i] = *(const short8v*)&As[p][(wy * 64 + i * 16 + mcol) * KP + quad * 8];
        #pragma unroll
        for (int j = 0; j < 2; ++j)
            b[j] = *(const short8v*)&Bs[p][(wx * 32 + j * 16 + mcol) * KP + quad * 8];
        #pragma unroll
        for (int i = 0; i < 4; ++i)
            #pragma unroll
            for (int j = 0; j < 2; ++j)
                acc[i][j] = __builtin_amdgcn_mfma_f32_16x16x32_bf16(a[i], b[j], acc[i][j], 0, 0, 0);

        if (more) {
            #pragma unroll
            for (int it = 0; it < 2; ++it) *(short8v*)&As[1 - p][rowA[it] * KP + kcA * 8] = pa[it];
            #pragma unroll
            for (int it = 0; it < 2; ++it) *(short4v*)&Bs[1 - p][rowB[it] * KP + kq * 4] = cvt4(pb[it]);
        }
        __syncthreads();
        p ^= 1;
    }

    #pragma unroll
    for (int i = 0; i < 4; ++i) {
        #pragma unroll
        for (int r = 0; r < 4; ++r) {
            int m = wy * 64 + i * 16 + quad * 4 + r;
            int s = sl[m];
            if (s < 0) continue;
            if (WRITE_Y) {
                short* yrow = ydown + (size_t)s * HH + n_base + wx * 32;
                #pragma unroll
                for (int j = 0; j < 2; ++j)
                    yrow[j * 16 + mcol] = f2bf(acc[i][j][r]);
            } else {
                float* orow = out + (size_t)(s >> 2) * HH + n_base + wx * 32;
                #pragma unroll
                for (int j = 0; j < 2; ++j)
                    atomicAdd(&orow[j * 16 + mcol], acc[i][j][r]);
            }
        }
    }
}

// ============== Kernel 4a: combine (weights pre-applied) ==============
__global__ __launch_bounds__(256) void combine_kernel(
    const float* __restrict__ x, const short* __restrict__ ydown,
    const int* __restrict__ kexp, const float* __restrict__ zero_w,
    float* __restrict__ out)
{
    const int t = blockIdx.x;
    const int c = threadIdx.x;   // float4 index
    const float4 xv = ((const float4*)(x + (size_t)t * HH))[c];
    const float zw = zero_w[t];
    float4 o;
    o.x = zw * xv.x; o.y = zw * xv.y; o.z = zw * xv.z; o.w = zw * xv.w;
    #pragma unroll
    for (int k = 0; k < TOPK; ++k) {
        int slot = t * TOPK + k;
        if (kexp[slot] < EE) {
            short4v y = *(const short4v*)&ydown[(size_t)slot * HH + c * 4];
            o.x += bf2f(y[0]); o.y += bf2f(y[1]);
            o.z += bf2f(y[2]); o.w += bf2f(y[3]);
        }
    }
    ((float4*)(out + (size_t)t * HH))[c] = o;
}

// ============== Kernel 4b: zero residual (fallback path) ==============
__global__ __launch_bounds__(256) void zero_resid_kernel(
    const float* __restrict__ x, const float* __restrict__ zero_w,
    float* __restrict__ out)
{
    const int t = blockIdx.x;
    const float zw = zero_w[t];
    const int tid = threadIdx.x;
    const float4 xv = ((const float4*)(x + (size_t)t * HH))[tid];
    float4* o = (float4*)(out + (size_t)t * HH);
    float4 ov = o[tid];
    ov.x += zw * xv.x; ov.y += zw * xv.y; ov.z += zw * xv.z; ov.w += zw * xv.w;
    o[tid] = ov;
}

extern "C" void kernel_launch(void* const* d_in, const int* in_sizes, int n_in,
                              void* d_out, int out_size, void* d_ws, size_t ws_size,
                              hipStream_t stream) {
    const float* x    = (const float*)d_in[0];
    const float* rw   = (const float*)d_in[1];
    const float* bias = (const float*)d_in[2];
    const float* wgu  = (const float*)d_in[3];
    const float* wd   = (const float*)d_in[4];
    float* out = (float*)d_out;

    char* ws = (char*)d_ws;
    int*   counts = (int*)ws;
    float* topk_w = (float*)(ws + 1024);
    float* zero_w = (float*)(ws + 17408);
    int*   kexp   = (int*)(ws + 21504);
    int*   slots  = (int*)(ws + 40960);
    short* xb     = (short*)(ws + 262144);
    short* hmid   = (short*)(ws + 2359296);
    short* ydown  = (short*)(ws + 6553600);

    const bool big = ws_size >= WS_NEED_COMBINE;

    hipMemsetAsync(counts, 0, EE * sizeof(int), stream);
    if (!big) hipMemsetAsync(out, 0, (size_t)out_size * sizeof(float), stream);

    xconv_kernel<<<dim3(TT * HH / (256 * 8)), dim3(256), 0, stream>>>(x, xb);
    router_kernel<<<dim3(TT / 2), dim3(64), 0, stream>>>(
        x, rw, bias, topk_w, zero_w, kexp, counts, slots);
    gate_up_kernel<<<dim3(II / GNP, EE, CAP / GM), dim3(256), 0, stream>>>(
        xb, wgu, counts, slots, topk_w, hmid);
    if (big) {
        down_kernel_t<1><<<dim3(HH / DN, EE, CAP / DM), dim3(256), 0, stream>>>(
            hmid, wd, counts, slots, ydown, out);
        combine_kernel<<<dim3(TT), dim3(256), 0, stream>>>(
            x, ydown, kexp, zero_w, out);
    } else {
        down_kernel_t<0><<<dim3(HH / DN, EE, CAP / DM), dim3(256), 0, stream>>>(
            hmid, wd, counts, slots, nullptr, out);
        zero_resid_kernel<<<dim3(TT), dim3(256), 0, stream>>>(x, zero_w, out);
    }
}

// Round 6
// 311.263 us; speedup vs baseline: 1.0637x; 1.0637x over previous
//
#include <hip/hip_runtime.h>
#include <hip/hip_cooperative_groups.h>
#include <hip/hip_bf16.h>
#include <math.h>

namespace cg = cooperative_groups;

#define TT   1024
#define HH   1024
#define II   512
#define EE   32
#define NE   40
#define TOPK 4
#define CAP  1024

#define GM  128   // m-tile (slots)
#define GNP 32    // gate/up pairs per tile -> 64 B-rows
#define GK  32    // k-slab
#define KP  40    // LDS pitch (bf16): 80 B, 16B-aligned, 2-way banks (free)
#define DN  64    // down n-tile (64 B-rows)

typedef __attribute__((ext_vector_type(4))) short short4v;
typedef __attribute__((ext_vector_type(8))) short short8v;
typedef __attribute__((ext_vector_type(4))) float floatx4;

static __device__ __forceinline__ short f2bf(float f) {
    unsigned u = __float_as_uint(f);
    unsigned r = (u + 0x7fffu + ((u >> 16) & 1u)) >> 16;
    return (short)(r & 0xffffu);
}
static __device__ __forceinline__ float bf2f(short s) {
    return __uint_as_float(((unsigned)(unsigned short)s) << 16);
}
#if defined(__has_builtin)
#if __has_builtin(__builtin_amdgcn_cvt_pk_bf16_f32)
#define HAVE_PK_BF16 1
#endif
#endif
static __device__ __forceinline__ unsigned pk2(float a, float b) {
#ifdef HAVE_PK_BF16
    typedef __attribute__((ext_vector_type(2))) __bf16 bf2t;
    union { bf2t v; unsigned u; } cv;
    cv.v = __builtin_amdgcn_cvt_pk_bf16_f32(a, b);
    return cv.u;
#else
    return (unsigned)(unsigned short)f2bf(a) | ((unsigned)(unsigned short)f2bf(b) << 16);
#endif
}
static __device__ __forceinline__ short4v cvt4(float4 v) {
    union { unsigned u[2]; short4v s; } cv;
    cv.u[0] = pk2(v.x, v.y); cv.u[1] = pk2(v.z, v.w);
    return cv.s;
}

// shared-memory block: 10240 + 5120 + 512 + 512 = 16384 B
struct SMem {
    short As[GM * KP];        // 128 rows
    short Bs[2 * GNP * KP];   // 64 rows (both GEMM phases)
    int   sl[GM];
    float wvs[GM];
};

// ---------------- workspace layout (bytes) ----------------
// counts @0, topk_w @1024, zero_w @17408, kexp @21504, slots @40960,
// xb @262144 (2MB), hmid @2359296 (4MB), ydown @6553600 (8MB)

// ================= Phase A: router (waves 0,1) + xconv (waves 2,3) ============
static __device__ __forceinline__ void phaseA(
    const int bx, const int tid,
    const float* __restrict__ x, const float* __restrict__ rw,
    const float* __restrict__ bias,
    float* __restrict__ topk_w, float* __restrict__ zero_w,
    int* __restrict__ kexp, int* __restrict__ counts,
    int* __restrict__ slots, short* __restrict__ xb)
{
    const int lane = tid & 63;
    const int w    = tid >> 6;

    if (w < 2) {
        const int t = bx * 2 + w;
        float xv[16];
        #pragma unroll
        for (int i = 0; i < 16; ++i) xv[i] = x[(size_t)t * HH + 64 * i + lane];

        float mylogit = -INFINITY;
        for (int e0 = 0; e0 < NE; e0 += 4) {
            const float* r0 = rw + (size_t)e0 * HH;
            float p[4] = { 0.f, 0.f, 0.f, 0.f };
            #pragma unroll
            for (int i = 0; i < 16; ++i) {
                int h = 64 * i + lane;
                #pragma unroll
                for (int j = 0; j < 4; ++j) p[j] += xv[i] * r0[(size_t)j * HH + h];
            }
            #pragma unroll
            for (int j = 0; j < 4; ++j) {
                #pragma unroll
                for (int off = 32; off > 0; off >>= 1) p[j] += __shfl_xor(p[j], off);
                if (lane == e0 + j) mylogit = p[j];
            }
        }

        float m = mylogit;
        #pragma unroll
        for (int off = 32; off > 0; off >>= 1) m = fmaxf(m, __shfl_xor(m, off));
        float pexp = (lane < NE) ? expf(mylogit - m) : 0.f;
        float s = pexp;
        #pragma unroll
        for (int off = 32; off > 0; off >>= 1) s += __shfl_xor(s, off);
        const float score = pexp / s;

        float val = (lane < NE) ? score + bias[lane] : -INFINITY;
        int   kidx[TOPK];
        float kw[TOPK];
        #pragma unroll
        for (int k = 0; k < TOPK; ++k) {
            float v = val; int idx = lane;
            #pragma unroll
            for (int off = 32; off > 0; off >>= 1) {
                float ov = __shfl_xor(v, off);
                int   oi = __shfl_xor(idx, off);
                if (ov > v || (ov == v && oi < idx)) { v = ov; idx = oi; }
            }
            kidx[k] = idx;
            kw[k]   = __shfl(score, idx);
            if (lane == idx) val = -INFINITY;
        }

        if (lane == 0) {
            float zw = 0.f;
            #pragma unroll
            for (int k = 0; k < TOPK; ++k) {
                int slot = t * TOPK + k;
                topk_w[slot] = kw[k];
                kexp[slot]   = kidx[k];
                if (kidx[k] < EE) {
                    int pos = atomicAdd(&counts[kidx[k]], 1);
                    slots[kidx[k] * CAP + pos] = slot;
                } else {
                    zw += kw[k];
                }
            }
            zero_w[t] = zw;
        }
    } else {
        const int t = bx * 2 + (w - 2);
        const float4* xr = (const float4*)(x + (size_t)t * HH);
        short4v* xbr = (short4v*)(xb + (size_t)t * HH);
        #pragma unroll
        for (int i = 0; i < 4; ++i) xbr[lane + 64 * i] = cvt4(xr[lane + 64 * i]);
    }
}

// ================= Phase B: gate_up bf16 MFMA + SiLU (weights pre-scaled) =====
static __device__ __forceinline__ void phaseB(
    const int bx, const int tid, SMem* sm,
    const short* __restrict__ xb, const float* __restrict__ wgu,
    const int* __restrict__ counts, const int* __restrict__ slots,
    const float* __restrict__ topk_w, short* __restrict__ hmid)
{
    const int e      = bx >> 4;
    const int c_base = (bx & 15) * GNP;
    const int cnt    = counts[e];
    const float* wb  = wgu + (size_t)e * (2 * II) * HH;

    const int lane = tid & 63;
    const int w    = tid >> 6;
    const int wy   = w & 1;
    const int wx   = w >> 1;
    const int quad = lane >> 4;
    const int mcol = lane & 15;

    for (int m_base = 0; m_base < cnt; m_base += GM) {
        if (tid < GM) {
            int m = m_base + tid;
            int s = (m < cnt) ? slots[e * CAP + m] : -1;
            sm->sl[tid]  = s;
            sm->wvs[tid] = (s >= 0) ? topk_w[s] : 0.f;
        }
        __syncthreads();

        const int kcA = tid & 3;
        int rowA[2]; int slA[2]; const short* pA[2];
        #pragma unroll
        for (int it = 0; it < 2; ++it) {
            rowA[it] = (tid >> 2) + 64 * it;
            int s = sm->sl[rowA[it]];
            slA[it] = s;
            pA[it] = xb + (size_t)((s >= 0 ? s : 0) >> 2) * HH + kcA * 8;
        }
        const int kq = tid & 7;
        int rowB[2]; const float* pB[2];
        #pragma unroll
        for (int it = 0; it < 2; ++it) {
            rowB[it] = (tid >> 3) + 32 * it;
            int grow = (rowB[it] < GNP) ? (c_base + rowB[it])
                                        : (II + c_base + rowB[it] - GNP);
            pB[it] = wb + (size_t)grow * HH + kq * 4;
        }

        floatx4 accg[4] = {};
        floatx4 accu[4] = {};
        short8v pa[2]; float4 pb[2];
        const short8v szv = { 0,0,0,0,0,0,0,0 };

        // prefetch slab 0 into registers
        #pragma unroll
        for (int it = 0; it < 2; ++it) pa[it] = (slA[it] >= 0) ? *(const short8v*)(pA[it]) : szv;
        #pragma unroll
        for (int it = 0; it < 2; ++it) pb[it] = *(const float4*)(pB[it]);

        for (int k0 = 0; k0 < HH; k0 += GK) {
            // store staged regs -> LDS (prev ds_reads drained by loop-end barrier)
            #pragma unroll
            for (int it = 0; it < 2; ++it) *(short8v*)&sm->As[rowA[it] * KP + kcA * 8] = pa[it];
            #pragma unroll
            for (int it = 0; it < 2; ++it) *(short4v*)&sm->Bs[rowB[it] * KP + kq * 4] = cvt4(pb[it]);
            __syncthreads();

            const int kn = k0 + GK;
            if (kn < HH) {   // issue next-slab loads; in flight during MFMA
                #pragma unroll
                for (int it = 0; it < 2; ++it) pa[it] = (slA[it] >= 0) ? *(const short8v*)(pA[it] + kn) : szv;
                #pragma unroll
                for (int it = 0; it < 2; ++it) pb[it] = *(const float4*)(pB[it] + kn);
            }

            short8v a[4], bg, bu;
            #pragma unroll
            for (int i = 0; i < 4; ++i)
                a[i] = *(const short8v*)&sm->As[(wy * 64 + i * 16 + mcol) * KP + quad * 8];
            bg = *(const short8v*)&sm->Bs[(wx * 16 + mcol) * KP + quad * 8];
            bu = *(const short8v*)&sm->Bs[(GNP + wx * 16 + mcol) * KP + quad * 8];
            #pragma unroll
            for (int i = 0; i < 4; ++i) {
                accg[i] = __builtin_amdgcn_mfma_f32_16x16x32_bf16(a[i], bg, accg[i], 0, 0, 0);
                accu[i] = __builtin_amdgcn_mfma_f32_16x16x32_bf16(a[i], bu, accu[i], 0, 0, 0);
            }
            __syncthreads();
        }

        #pragma unroll
        for (int i = 0; i < 4; ++i) {
            #pragma unroll
            for (int r = 0; r < 4; ++r) {
                int m = wy * 64 + i * 16 + quad * 4 + r;
                int s = sm->sl[m];
                if (s < 0) continue;
                float g = accg[i][r], u = accu[i][r];
                float valf = sm->wvs[m] * g * u / (1.f + __expf(-g));
                hmid[(size_t)s * II + c_base + wx * 16 + mcol] = f2bf(valf);
            }
        }
        __syncthreads();
    }
}

// ================= Phase C: down bf16 MFMA -> ydown ===========================
static __device__ __forceinline__ void phaseC(
    const int bx, const int tid, SMem* sm,
    const short* __restrict__ hmid, const float* __restrict__ wd,
    const int* __restrict__ counts, const int* __restrict__ slots,
    short* __restrict__ ydown)
{
    const int e      = bx >> 4;
    const int n_base = (bx & 15) * DN;
    const int cnt    = counts[e];
    const float* wb  = wd + (size_t)e * HH * II;

    const int lane = tid & 63;
    const int w    = tid >> 6;
    const int wy   = w & 1;
    const int wx   = w >> 1;
    const int quad = lane >> 4;
    const int mcol = lane & 15;

    for (int m_base = 0; m_base < cnt; m_base += GM) {
        if (tid < GM) {
            int m = m_base + tid;
            sm->sl[tid] = (m < cnt) ? slots[e * CAP + m] : -1;
        }
        __syncthreads();

        const int kcA = tid & 3;
        int rowA[2]; int slA[2]; const short* pA[2];
        #pragma unroll
        for (int it = 0; it < 2; ++it) {
            rowA[it] = (tid >> 2) + 64 * it;
            int s = sm->sl[rowA[it]];
            slA[it] = s;
            pA[it] = hmid + (size_t)(s >= 0 ? s : 0) * II + kcA * 8;
        }
        const int kq = tid & 7;
        int rowB[2]; const float* pB[2];
        #pragma unroll
        for (int it = 0; it < 2; ++it) {
            rowB[it] = (tid >> 3) + 32 * it;
            pB[it] = wb + (size_t)(n_base + rowB[it]) * II + kq * 4;
        }

        floatx4 acc[4][2] = {};
        short8v pa[2]; float4 pb[2];
        const short8v szv = { 0,0,0,0,0,0,0,0 };

        #pragma unroll
        for (int it = 0; it < 2; ++it) pa[it] = (slA[it] >= 0) ? *(const short8v*)(pA[it]) : szv;
        #pragma unroll
        for (int it = 0; it < 2; ++it) pb[it] = *(const float4*)(pB[it]);

        for (int k0 = 0; k0 < II; k0 += GK) {
            #pragma unroll
            for (int it = 0; it < 2; ++it) *(short8v*)&sm->As[rowA[it] * KP + kcA * 8] = pa[it];
            #pragma unroll
            for (int it = 0; it < 2; ++it) *(short4v*)&sm->Bs[rowB[it] * KP + kq * 4] = cvt4(pb[it]);
            __syncthreads();

            const int kn = k0 + GK;
            if (kn < II) {
                #pragma unroll
                for (int it = 0; it < 2; ++it) pa[it] = (slA[it] >= 0) ? *(const short8v*)(pA[it] + kn) : szv;
                #pragma unroll
                for (int it = 0; it < 2; ++it) pb[it] = *(const float4*)(pB[it] + kn);
            }

            short8v a[4], b[2];
            #pragma unroll
            for (int i = 0; i < 4; ++i)
                a[i] = *(const short8v*)&sm->As[(wy * 64 + i * 16 + mcol) * KP + quad * 8];
            #pragma unroll
            for (int j = 0; j < 2; ++j)
                b[j] = *(const short8v*)&sm->Bs[(wx * 32 + j * 16 + mcol) * KP + quad * 8];
            #pragma unroll
            for (int i = 0; i < 4; ++i)
                #pragma unroll
                for (int j = 0; j < 2; ++j)
                    acc[i][j] = __builtin_amdgcn_mfma_f32_16x16x32_bf16(a[i], b[j], acc[i][j], 0, 0, 0);
            __syncthreads();
        }

        #pragma unroll
        for (int i = 0; i < 4; ++i) {
            #pragma unroll
            for (int r = 0; r < 4; ++r) {
                int m = wy * 64 + i * 16 + quad * 4 + r;
                int s = sm->sl[m];
                if (s < 0) continue;
                short* yrow = ydown + (size_t)s * HH + n_base + wx * 32;
                #pragma unroll
                for (int j = 0; j < 2; ++j)
                    yrow[j * 16 + mcol] = f2bf(acc[i][j][r]);
            }
        }
        __syncthreads();
    }
}

// ================= Phase D: combine ===========================================
static __device__ __forceinline__ void phaseD(
    const int bx, const int tid,
    const float* __restrict__ x, const short* __restrict__ ydown,
    const int* __restrict__ kexp, const float* __restrict__ zero_w,
    float* __restrict__ out)
{
    #pragma unroll
    for (int j = 0; j < 2; ++j) {
        const int t = bx * 2 + j;
        const float4 xvv = ((const float4*)(x + (size_t)t * HH))[tid];
        const float zw = zero_w[t];
        float4 o;
        o.x = zw * xvv.x; o.y = zw * xvv.y; o.z = zw * xvv.z; o.w = zw * xvv.w;
        #pragma unroll
        for (int k = 0; k < TOPK; ++k) {
            int slot = t * TOPK + k;
            if (kexp[slot] < EE) {
                short4v y = *(const short4v*)&ydown[(size_t)slot * HH + tid * 4];
                o.x += bf2f(y[0]); o.y += bf2f(y[1]);
                o.z += bf2f(y[2]); o.w += bf2f(y[3]);
            }
        }
        ((float4*)(out + (size_t)t * HH))[tid] = o;
    }
}

// ================= fused cooperative kernel ===================================
__global__ __launch_bounds__(256, 2) void fused_moe(
    const float* __restrict__ x, const float* __restrict__ rw,
    const float* __restrict__ bias, const float* __restrict__ wgu,
    const float* __restrict__ wd, float* __restrict__ out,
    int* __restrict__ counts, float* __restrict__ topk_w,
    float* __restrict__ zero_w, int* __restrict__ kexp,
    int* __restrict__ slots, short* __restrict__ xb,
    short* __restrict__ hmid, short* __restrict__ ydown)
{
    cg::grid_group grid = cg::this_grid();
    __shared__ SMem sm;
    const int bx = blockIdx.x, tid = threadIdx.x;

    phaseA(bx, tid, x, rw, bias, topk_w, zero_w, kexp, counts, slots, xb);
    __threadfence(); grid.sync();
    phaseB(bx, tid, &sm, xb, wgu, counts, slots, topk_w, hmid);
    __threadfence(); grid.sync();
    phaseC(bx, tid, &sm, hmid, wd, counts, slots, ydown);
    __threadfence(); grid.sync();
    phaseD(bx, tid, x, ydown, kexp, zero_w, out);
}

// ================= fallback: phases as separate kernels =======================
__global__ __launch_bounds__(256, 2) void kA(
    const float* __restrict__ x, const float* __restrict__ rw,
    const float* __restrict__ bias, float* __restrict__ topk_w,
    float* __restrict__ zero_w, int* __restrict__ kexp,
    int* __restrict__ counts, int* __restrict__ slots, short* __restrict__ xb)
{
    phaseA(blockIdx.x, threadIdx.x, x, rw, bias, topk_w, zero_w, kexp, counts, slots, xb);
}
__global__ __launch_bounds__(256, 2) void kB(
    const short* __restrict__ xb, const float* __restrict__ wgu,
    const int* __restrict__ counts, const int* __restrict__ slots,
    const float* __restrict__ topk_w, short* __restrict__ hmid)
{
    __shared__ SMem sm;
    phaseB(blockIdx.x, threadIdx.x, &sm, xb, wgu, counts, slots, topk_w, hmid);
}
__global__ __launch_bounds__(256, 2) void kC(
    const short* __restrict__ hmid, const float* __restrict__ wd,
    const int* __restrict__ counts, const int* __restrict__ slots,
    short* __restrict__ ydown)
{
    __shared__ SMem sm;
    phaseC(blockIdx.x, threadIdx.x, &sm, hmid, wd, counts, slots, ydown);
}
__global__ __launch_bounds__(256, 2) void kD(
    const float* __restrict__ x, const short* __restrict__ ydown,
    const int* __restrict__ kexp, const float* __restrict__ zero_w,
    float* __restrict__ out)
{
    phaseD(blockIdx.x, threadIdx.x, x, ydown, kexp, zero_w, out);
}

extern "C" void kernel_launch(void* const* d_in, const int* in_sizes, int n_in,
                              void* d_out, int out_size, void* d_ws, size_t ws_size,
                              hipStream_t stream) {
    const float* x    = (const float*)d_in[0];
    const float* rw   = (const float*)d_in[1];
    const float* bias = (const float*)d_in[2];
    const float* wgu  = (const float*)d_in[3];
    const float* wd   = (const float*)d_in[4];
    float* out = (float*)d_out;

    char* ws = (char*)d_ws;
    int*   counts = (int*)ws;
    float* topk_w = (float*)(ws + 1024);
    float* zero_w = (float*)(ws + 17408);
    int*   kexp   = (int*)(ws + 21504);
    int*   slots  = (int*)(ws + 40960);
    short* xb     = (short*)(ws + 262144);
    short* hmid   = (short*)(ws + 2359296);
    short* ydown  = (short*)(ws + 6553600);

    hipMemsetAsync(counts, 0, EE * sizeof(int), stream);

    // capture-safe host-side occupancy pre-check (deterministic per call)
    int nb = 0;
    hipError_t qerr = hipOccupancyMaxActiveBlocksPerMultiprocessor(&nb, fused_moe, 256, 0);
    bool launched = false;
    if (qerr == hipSuccess && nb >= 2) {
        void* args[] = {
            (void*)&x, (void*)&rw, (void*)&bias, (void*)&wgu, (void*)&wd,
            (void*)&out, (void*)&counts, (void*)&topk_w, (void*)&zero_w,
            (void*)&kexp, (void*)&slots, (void*)&xb, (void*)&hmid, (void*)&ydown
        };
        hipError_t lerr = hipLaunchCooperativeKernel((const void*)fused_moe,
                                                     dim3(512), dim3(256),
                                                     args, 0, stream);
        launched = (lerr == hipSuccess);
    }
    if (!launched) {
        kA<<<dim3(512), dim3(256), 0, stream>>>(x, rw, bias, topk_w, zero_w, kexp, counts, slots, xb);
        kB<<<dim3(512), dim3(256), 0, stream>>>(xb, wgu, counts, slots, topk_w, hmid);
        kC<<<dim3(512), dim3(256), 0, stream>>>(hmid, wd, counts, slots, ydown);
        kD<<<dim3(512), dim3(256), 0, stream>>>(x, ydown, kexp, zero_w, out);
    }
}